// Round 2
// baseline (246.404 us; speedup 1.0000x reference)
//
#include <hip/hip_runtime.h>
#include <hip/hip_bf16.h>

#define NN 10000
#define EE 160000
#define BB 16
#define PP 12
#define CC 32
#define FPn 24                 // F*P
#define XTOT (BB*NN*FPn)       // 3,840,000 elements

__device__ __forceinline__ float bfu2f(unsigned short u){
    union { unsigned int i; float f; } c; c.i = ((unsigned int)u) << 16; return c.f;
}
__device__ __forceinline__ unsigned short f2bfu(float f){
    union { float f; unsigned int i; } c; c.f = f;
    unsigned int r = c.i + 0x7FFFu + ((c.i >> 16) & 1u);   // RN-even
    return (unsigned short)(r >> 16);
}
__device__ __forceinline__ float ldf(const void* p, int i, int isbf){
    return isbf ? bfu2f(((const unsigned short*)p)[i]) : ((const float*)p)[i];
}
__device__ __forceinline__ void up2(unsigned int u, float& a, float& b){
    union { unsigned int i; float f; } c;
    c.i = u << 16;          a = c.f;
    c.i = u & 0xFFFF0000u;  b = c.f;
}
__device__ __forceinline__ float fast_rcp(float x){ return __builtin_amdgcn_rcpf(x); }

// ---------- K-1: dtype sniffer. bf16 N(0,1) data -> exponent byte in [110,140]. ----------
__global__ void k_detect(const unsigned short* __restrict__ xu, int* __restrict__ flag){
    if (threadIdx.x == 0 && blockIdx.x == 0){
        int c1 = 0;
        for (int i = 0; i < 64; i++){
            unsigned short u = xu[2*i];
            int e = (u >> 7) & 0xFF;
            if (e >= 110 && e <= 140) c1++;
        }
        flag[0] = (c1 >= 36) ? 1 : 0;   // 1 = inputs are bf16, 0 = fp32
    }
}

// ---------- K0: canonicalize x -> bf16, node-major [n][b][fp] ----------
__global__ void k_convx(const void* __restrict__ x, const int* __restrict__ flag,
                        unsigned short* __restrict__ xc){
    int t  = blockIdx.x*blockDim.x + threadIdx.x;   // < 960000
    int o0 = t*4;
    int n  = o0 / 384;
    int j  = o0 - n*384;
    int b  = j / 24;
    int fp = j - b*24;
    int src = b*(NN*FPn) + n*FPn + fp;              // 4 consecutive (fp%4==0, never crosses b)
    ushort4 r;
    if (flag[0]){
        r = *(const ushort4*)((const unsigned short*)x + src);
    } else {
        float4 f = *(const float4*)((const float*)x + src);
        r.x = f2bfu(f.x); r.y = f2bfu(f.y); r.z = f2bfu(f.z); r.w = f2bfu(f.w);
    }
    *(ushort4*)(xc + o0) = r;
}

// ---------- K0b: canonicalize edge_weight -> fp32 ----------
__global__ void k_convew(const void* __restrict__ ew, const int* __restrict__ flag,
                         float* __restrict__ ewc){
    int i = blockIdx.x*blockDim.x + threadIdx.x;    // exactly EE
    ewc[i] = ldf(ew, i, flag[0]);
}

// ---------- K1: effective (collapsed) weights + softmax(attention) ----------
// wbuf: 0:s0[32] 32:s1[32] 64:sb[32] 96:h0[32] 128:h1[32] 160:hb[32]
//       192:probs[12] 204:lob[12] 216:LoW[32*12]
__global__ void k_weights(const void* Wz, const void* bz, const void* LzW, const void* lzb,
                          const void* Wh, const void* bh, const void* LhW, const void* lhb,
                          const void* att, const void* LoW, const void* lob,
                          const int* __restrict__ flag, float* __restrict__ wbuf){
    int t = threadIdx.x;
    int isbf = flag[0];
    if (t < CC){
        int c = t;
        float s0=0.f, s1=0.f, sb=ldf(lzb,c,isbf);
        for (int k=0;k<CC;k++){
            float w = ldf(LzW, k*CC+c, isbf);       // first 32 rows of [64,32]
            s0 += ldf(Wz, k,    isbf)*w;
            s1 += ldf(Wz, CC+k, isbf)*w;
            sb += ldf(bz, k,    isbf)*w;
        }
        wbuf[c]=s0; wbuf[32+c]=s1; wbuf[64+c]=sb;
        float h0=0.f, h1=0.f, hb=ldf(lhb,c,isbf);
        for (int k=0;k<CC;k++){
            float w = ldf(LhW, k*CC+c, isbf);
            h0 += ldf(Wh, k,    isbf)*w;
            h1 += ldf(Wh, CC+k, isbf)*w;
            hb += ldf(bh, k,    isbf)*w;
        }
        wbuf[96+c]=h0; wbuf[128+c]=h1; wbuf[160+c]=hb;
        for (int q=0;q<PP;q++) wbuf[216 + c*PP + q] = ldf(LoW, c*PP+q, isbf);
    } else if (t == 32){
        float a[PP]; float m = -1e30f;
        for (int p=0;p<PP;p++){ a[p]=ldf(att,p,isbf); m = fmaxf(m, a[p]); }
        float s=0.f;
        for (int p=0;p<PP;p++){ a[p]=__expf(a[p]-m); s += a[p]; }
        float r = 1.f/s;
        for (int p=0;p<PP;p++) wbuf[192+p] = a[p]*r;
    } else if (t == 33){
        for (int q=0;q<PP;q++) wbuf[204+q] = ldf(lob,q,isbf);
    }
}

// ---------- K2: init deg (self-loop w=1) and counts ----------
__global__ void k_init(float* __restrict__ deg, int* __restrict__ cnt){
    int n = blockIdx.x*blockDim.x + threadIdx.x;
    if (n < NN){ deg[n] = 1.0f; cnt[n] = 0; }
}

// ---------- K3: degree + histogram over dst ----------
__global__ void k_deg(const int* __restrict__ dst, const float* __restrict__ ewc,
                      float* __restrict__ deg, int* __restrict__ cnt){
    int e = blockIdx.x*blockDim.x + threadIdx.x;
    if (e < EE){
        int d = dst[e];
        atomicAdd(&deg[d], ewc[e]);
        atomicAdd(&cnt[d], 1);
    }
}

// ---------- K4: dinv ----------
__global__ void k_dinv(const float* __restrict__ deg, float* __restrict__ dinv){
    int n = blockIdx.x*blockDim.x + threadIdx.x;
    if (n < NN){
        float d = deg[n];
        dinv[n] = (d > 0.f) ? rsqrtf(d) : 0.f;
    }
}

// ---------- K5: single-block exclusive scan -> rowp, nxt ----------
__global__ void k_scan(const int* __restrict__ cnt, int* __restrict__ rowp, int* __restrict__ nxt){
    __shared__ int sums[256];
    int tid = threadIdx.x;
    const int CH = (NN + 255)/256;   // 40
    int lo = tid*CH, hi = lo+CH; if (hi > NN) hi = NN; if (lo > NN) lo = NN;
    int s = 0;
    for (int j=lo;j<hi;j++) s += cnt[j];
    sums[tid] = s;
    __syncthreads();
    for (int off=1; off<256; off<<=1){
        int t = (tid >= off) ? sums[tid-off] : 0;
        __syncthreads();
        sums[tid] += t;
        __syncthreads();
    }
    int run = sums[tid] - s;
    if (tid == 0) rowp[0] = 0;
    for (int j=lo;j<hi;j++){
        nxt[j] = run;
        run += cnt[j];
        rowp[j+1] = run;
    }
}

// ---------- K6: scatter edges into CSR ----------
__global__ void k_scatter(const int* __restrict__ src, const int* __restrict__ dst,
                          const float* __restrict__ ewc, const float* __restrict__ dinv,
                          int* __restrict__ nxt, int* __restrict__ col, float* __restrict__ val){
    int e = blockIdx.x*blockDim.x + threadIdx.x;
    if (e < EE){
        int s = src[e], d = dst[e];
        float nv = dinv[s] * ewc[e] * dinv[d];
        int pos = atomicAdd(&nxt[d], 1);
        col[pos] = s;
        val[pos] = nv;
    }
}

// ---------- K7: fused aggregate + collapsed GRU + output ----------
// 256 threads = 16 nodes/block. Phase 1: thread (g=tid>>4 node, l=tid&15 batch)
// accumulates y[b=l, n, fp<24] over CSR row n; x_c is node-major so each edge is
// one contiguous 768B block. Phase 2: thread (b=tid>>4, gg=tid&15) does the GRU.
__global__ __launch_bounds__(256) void k_fused(const unsigned short* __restrict__ xc,
        const int* __restrict__ rowp, const int* __restrict__ col,
        const float* __restrict__ val, const float* __restrict__ dinv,
        const float* __restrict__ wbuf, void* __restrict__ outv,
        const int* __restrict__ flag){
    __shared__ float ys[16*388];
    __shared__ float w[640];
    int tid = threadIdx.x;
    for (int i=tid; i<600; i+=256) w[i] = wbuf[i];

    int g = tid >> 4;          // node within block
    int l = tid & 15;          // batch
    int n0 = blockIdx.x * 16;
    int n  = n0 + g;
    int e0 = rowp[n], e1 = rowp[n+1];

    float acc[24];
    #pragma unroll
    for (int k=0;k<24;k++) acc[k] = 0.f;

    for (int e=e0; e<e1; ++e){
        int s   = col[e];
        float v = val[e];
        const uint4* xp = (const uint4*)(xc + s*384 + l*24);
        uint4 q0 = xp[0], q1 = xp[1], q2 = xp[2];
        float f[24];
        up2(q0.x,f[0],f[1]);   up2(q0.y,f[2],f[3]);   up2(q0.z,f[4],f[5]);   up2(q0.w,f[6],f[7]);
        up2(q1.x,f[8],f[9]);   up2(q1.y,f[10],f[11]); up2(q1.z,f[12],f[13]); up2(q1.w,f[14],f[15]);
        up2(q2.x,f[16],f[17]); up2(q2.y,f[18],f[19]); up2(q2.z,f[20],f[21]); up2(q2.w,f[22],f[23]);
        #pragma unroll
        for (int k=0;k<24;k++) acc[k] = fmaf(v, f[k], acc[k]);
    }
    {   // self loop, weight dinv[n]^2
        float di = dinv[n];
        float v  = di*di;
        const uint4* xp = (const uint4*)(xc + n*384 + l*24);
        uint4 q0 = xp[0], q1 = xp[1], q2 = xp[2];
        float f[24];
        up2(q0.x,f[0],f[1]);   up2(q0.y,f[2],f[3]);   up2(q0.z,f[4],f[5]);   up2(q0.w,f[6],f[7]);
        up2(q1.x,f[8],f[9]);   up2(q1.y,f[10],f[11]); up2(q1.z,f[12],f[13]); up2(q1.w,f[14],f[15]);
        up2(q2.x,f[16],f[17]); up2(q2.y,f[18],f[19]); up2(q2.z,f[20],f[21]); up2(q2.w,f[22],f[23]);
        #pragma unroll
        for (int k=0;k<24;k++) acc[k] = fmaf(v, f[k], acc[k]);
    }
    #pragma unroll
    for (int k=0;k<24;k++) ys[g*388 + l*24 + k] = acc[k];
    __syncthreads();

    int b  = tid >> 4;         // batch
    int gg = tid & 15;         // node within block
    int n2 = n0 + gg;
    float y[24];
    #pragma unroll
    for (int i=0;i<24;i++) y[i] = ys[gg*388 + b*24 + i];
    float pr[12], o[12];
    #pragma unroll
    for (int p=0;p<12;p++) pr[p] = w[192+p];
    #pragma unroll
    for (int q=0;q<12;q++) o[q]  = w[204+q];

    for (int c=0;c<CC;c++){
        float wz0=w[c], wz1=w[32+c], bz=w[64+c];
        float wh0=w[96+c], wh1=w[128+c], bh=w[160+c];
        float a = 0.f;
        #pragma unroll
        for (int p=0;p<12;p++){
            float y0 = y[p], y1 = y[12+p];              // fp = f*12+p
            float zs = fmaf(y1, wz1, fmaf(y0, wz0, bz));
            float hs = fmaf(y1, wh1, fmaf(y0, wh0, bh));
            float oz = fast_rcp(1.f + __expf(zs));                 // 1 - sigmoid(zs)
            float th = 1.f - 2.f*fast_rcp(1.f + __expf(2.f*hs));   // tanh(hs)
            a = fmaf(pr[p], oz*th, a);
        }
        a = fmaxf(a, 0.f);                                          // relu(H_acc)
        #pragma unroll
        for (int q=0;q<12;q++) o[q] = fmaf(a, w[216 + c*12 + q], o[q]);
    }
    if (flag[0]){
        __hip_bfloat16* op = (__hip_bfloat16*)outv + (b*NN + n2)*PP;
        #pragma unroll
        for (int q=0;q<12;q++) op[q] = __float2bfloat16(o[q]);
    } else {
        float* op = (float*)outv + (b*NN + n2)*PP;
        #pragma unroll
        for (int q=0;q<12;q++) op[q] = o[q];
    }
}

extern "C" void kernel_launch(void* const* d_in, const int* in_sizes, int n_in,
                              void* d_out, int out_size, void* d_ws, size_t ws_size,
                              hipStream_t stream) {
    const void* x   = d_in[0];                 // [B,N,F,P] bf16 OR fp32 (sniffed)
    const int*  ei  = (const int*)d_in[1];     // [2,E]
    const void* ew  = d_in[2];
    const void* Wz  = d_in[3];
    const void* bz  = d_in[4];
    const void* LzW = d_in[5];
    const void* lzb = d_in[6];
    // d_in[7..10]: W_r/b_r/lin_r_W/lin_r_b dead (H0==0)
    const void* Wh  = d_in[11];
    const void* bh  = d_in[12];
    const void* LhW = d_in[13];
    const void* lhb = d_in[14];
    const void* att = d_in[15];
    const void* LoW = d_in[16];
    const void* lob = d_in[17];

    const int* srcI = ei;
    const int* dstI = ei + EE;

    char* ws = (char*)d_ws;
    size_t off = 0;
    auto alloc = [&](size_t bytes){ void* p = ws + off; off += (bytes + 255)/256*256; return p; };
    int*            flag = (int*)alloc(16*4);
    float*          wbuf = (float*)alloc(640*4);
    unsigned short* xc   = (unsigned short*)alloc((size_t)XTOT*2);   // 7.68 MB
    float*          ewc  = (float*)alloc(EE*4);
    float*          deg  = (float*)alloc(NN*4);
    float*          dinv = (float*)alloc(NN*4);
    int*            cnt  = (int*)alloc(NN*4);
    int*            rowp = (int*)alloc((NN+1)*4);
    int*            nxt  = (int*)alloc(NN*4);
    int*            col  = (int*)alloc(EE*4);
    float*          val  = (float*)alloc(EE*4);

    const int nb_n = (NN + 255)/256;   // 40
    const int nb_e = EE/256;           // 625 exact
    const int nb_x = XTOT/4/256;       // 3750 exact

    hipLaunchKernelGGL(k_detect,  dim3(1),    dim3(64),  0, stream, (const unsigned short*)x, flag);
    hipLaunchKernelGGL(k_convx,   dim3(nb_x), dim3(256), 0, stream, x, flag, xc);
    hipLaunchKernelGGL(k_convew,  dim3(nb_e), dim3(256), 0, stream, ew, flag, ewc);
    hipLaunchKernelGGL(k_weights, dim3(1),    dim3(64),  0, stream,
                       Wz, bz, LzW, lzb, Wh, bh, LhW, lhb, att, LoW, lob, flag, wbuf);
    hipLaunchKernelGGL(k_init,    dim3(nb_n), dim3(256), 0, stream, deg, cnt);
    hipLaunchKernelGGL(k_deg,     dim3(nb_e), dim3(256), 0, stream, dstI, ewc, deg, cnt);
    hipLaunchKernelGGL(k_dinv,    dim3(nb_n), dim3(256), 0, stream, deg, dinv);
    hipLaunchKernelGGL(k_scan,    dim3(1),    dim3(256), 0, stream, cnt, rowp, nxt);
    hipLaunchKernelGGL(k_scatter, dim3(nb_e), dim3(256), 0, stream, srcI, dstI, ewc, dinv, nxt, col, val);
    hipLaunchKernelGGL(k_fused,   dim3(NN/16),dim3(256), 0, stream,
                       xc, rowp, col, val, dinv, wbuf, d_out, flag);
}

// Round 3
// 189.254 us; speedup vs baseline: 1.3020x; 1.3020x over previous
//
#include <hip/hip_runtime.h>
#include <hip/hip_bf16.h>

#define NN 10000
#define EE 160000
#define BB 16
#define PP 12
#define CC 32
#define XTOT (BB*NN*24)        // 3,840,000 bf16 elements in xc

__device__ __forceinline__ float fast_rcp(float x){ return __builtin_amdgcn_rcpf(x); }
__device__ __forceinline__ float fast_exp2(float x){
#if __has_builtin(__builtin_amdgcn_exp2f)
    return __builtin_amdgcn_exp2f(x);
#else
    return exp2f(x);
#endif
}
__device__ __forceinline__ unsigned short f2bfu(float f){
    union { float f; unsigned int i; } c; c.f = f;
    unsigned int r = c.i + 0x7FFFu + ((c.i >> 16) & 1u);   // RN-even
    return (unsigned short)(r >> 16);
}
__device__ __forceinline__ void up2(unsigned int u, float& a, float& b){
    union { unsigned int i; float f; } c;
    c.i = u << 16;          a = c.f;
    c.i = u & 0xFFFF0000u;  b = c.f;
}
__device__ __forceinline__ void unp24(uint4 q0, uint4 q1, uint4 q2, float* f){
    up2(q0.x,f[0],f[1]);   up2(q0.y,f[2],f[3]);   up2(q0.z,f[4],f[5]);   up2(q0.w,f[6],f[7]);
    up2(q1.x,f[8],f[9]);   up2(q1.y,f[10],f[11]); up2(q1.z,f[12],f[13]); up2(q1.w,f[14],f[15]);
    up2(q2.x,f[16],f[17]); up2(q2.y,f[18],f[19]); up2(q2.z,f[20],f[21]); up2(q2.w,f[22],f[23]);
}

// ============ K1 (grid 3751): convx -> bf16 node-major; deg/cnt histogram; weights ============
// wbuf layout (fp32): [c*8 +0..5] = {wz0,wz1,bz}*log2e, {wh0,wh1,bh}*2log2e  (c<32)
//                     256: probs[12]   268: lob[12]   288: LoW packed [c][q] (32*12)
__global__ __launch_bounds__(256) void k_stage(const float* __restrict__ x,
        const float* __restrict__ ew, const int* __restrict__ dst,
        unsigned short* __restrict__ xc, float* __restrict__ deg, int* __restrict__ cnt,
        const float* __restrict__ Wz, const float* __restrict__ bz,
        const float* __restrict__ LzW, const float* __restrict__ lzb,
        const float* __restrict__ Wh, const float* __restrict__ bh,
        const float* __restrict__ LhW, const float* __restrict__ lhb,
        const float* __restrict__ att, const float* __restrict__ LoW,
        const float* __restrict__ lob, float* __restrict__ wbuf){
    const float L2E = 1.4426950408889634f;
    int blk = blockIdx.x, tid = threadIdx.x;
    if (blk < 3750){
        int t  = blk*256 + tid;            // < 960000
        int o0 = t*4;
        int n  = o0 / 384;
        int j  = o0 - n*384;
        int b  = j / 24;
        int fp = j - b*24;                  // fp%4==0, never crosses b
        float4 f = *(const float4*)(x + b*(NN*24) + n*24 + fp);
        ushort4 r; r.x=f2bfu(f.x); r.y=f2bfu(f.y); r.z=f2bfu(f.z); r.w=f2bfu(f.w);
        *(ushort4*)(xc + o0) = r;
        if (blk < 625){
            int e = blk*256 + tid;          // < 160000
            int d = dst[e];
            atomicAdd(&deg[d], ew[e]);
            atomicAdd(&cnt[d], 1);
        }
    } else {                                // blk == 3750: weights
        int c = tid;
        if (c < CC){
            float s0=0.f,s1=0.f,sb=lzb[c], h0=0.f,h1=0.f,hb=lhb[c];
            for (int k=0;k<CC;k++){
                float wz = LzW[k*CC+c];     // first 32 rows of [64,32]
                s0 += Wz[k]*wz; s1 += Wz[CC+k]*wz; sb += bz[k]*wz;
                float wh = LhW[k*CC+c];
                h0 += Wh[k]*wh; h1 += Wh[CC+k]*wh; hb += bh[k]*wh;
            }
            float* wp = wbuf + c*8;
            wp[0]=s0*L2E; wp[1]=s1*L2E; wp[2]=sb*L2E;
            wp[3]=h0*(2.f*L2E); wp[4]=h1*(2.f*L2E); wp[5]=hb*(2.f*L2E);
            wp[6]=0.f; wp[7]=0.f;
            for (int q=0;q<PP;q++) wbuf[288 + c*PP + q] = LoW[c*PP+q];
        } else if (c == 32){
            float a[PP]; float m = -1e30f;
            for (int p=0;p<PP;p++){ a[p]=att[p]; m = fmaxf(m, a[p]); }
            float s=0.f;
            for (int p=0;p<PP;p++){ a[p]=__expf(a[p]-m); s += a[p]; }
            float r = 1.f/s;
            for (int p=0;p<PP;p++) wbuf[256+p] = a[p]*r;
        } else if (c == 33){
            for (int q=0;q<PP;q++) wbuf[268+q] = lob[q];
        }
    }
}

// ============ K2: single-block exclusive scan (1024 threads) ============
__global__ __launch_bounds__(1024) void k_scan(const int* __restrict__ cnt,
        int* __restrict__ rowp, int* __restrict__ nxt){
    __shared__ int sums[1024];
    int tid = threadIdx.x;
    int lo = tid*10, hi = lo+10;
    if (lo > NN) lo = NN;
    if (hi > NN) hi = NN;
    int s = 0;
    for (int j=lo;j<hi;j++) s += cnt[j];
    sums[tid] = s;
    __syncthreads();
    for (int off=1; off<1024; off<<=1){
        int t = (tid >= off) ? sums[tid-off] : 0;
        __syncthreads();
        sums[tid] += t;
        __syncthreads();
    }
    int run = sums[tid] - s;               // exclusive prefix
    if (tid == 0) rowp[0] = 0;
    for (int j=lo;j<hi;j++){
        nxt[j] = run;
        run += cnt[j];
        rowp[j+1] = run;
    }
}

// ============ K3: scatter edges into CSR with norm values ============
__global__ __launch_bounds__(256) void k_scatter(const int* __restrict__ src,
        const int* __restrict__ dst, const float* __restrict__ ew,
        const float* __restrict__ deg, int* __restrict__ nxt,
        int* __restrict__ col, float* __restrict__ val){
    int e = blockIdx.x*256 + threadIdx.x;  // grid covers exactly EE
    int s = src[e], d = dst[e];
    float v = rsqrtf(deg[s]+1.0f) * ew[e] * rsqrtf(deg[d]+1.0f);
    int pos = atomicAdd(&nxt[d], 1);
    col[pos] = s;
    val[pos] = v;
}

// ============ K4: fused aggregate + collapsed GRU + output ============
// 128 threads = 4 nodes. Thread (g=tid>>5 node, h=(tid>>4)&1 edge-half, l=tid&15 batch):
// aggregates y[b=l, n, fp<24] over every other CSR edge; halves combined via shfl_xor(16);
// epilogue c-split across halves (h -> c in [16h,16h+16)), o combined via shfl_xor(16).
// No LDS, no barriers.
__global__ __launch_bounds__(128) void k_fused(const unsigned short* __restrict__ xc,
        const int* __restrict__ rowp, const int* __restrict__ col,
        const float* __restrict__ val, const float* __restrict__ deg,
        const float* __restrict__ wbuf, float* __restrict__ out){
    int tid = threadIdx.x;
    int g = tid >> 5, h = (tid >> 4) & 1, l = tid & 15;
    int n = blockIdx.x*4 + g;
    int e0 = rowp[n], e1 = rowp[n+1];

    float acc[24];
    #pragma unroll
    for (int k=0;k<24;k++) acc[k] = 0.f;
    const unsigned short* xl = xc + l*24;      // + s*384 per edge (16B-aligned)

    int e = e0 + h;
    for (; e + 2 < e1; e += 4){                // 2 edges of this half per iter
        int s1 = col[e],  s2 = col[e+2];
        float v1 = val[e], v2 = val[e+2];
        const uint4* p1 = (const uint4*)(xl + s1*384);
        const uint4* p2 = (const uint4*)(xl + s2*384);
        uint4 qa0=p1[0], qa1=p1[1], qa2=p1[2];
        uint4 qb0=p2[0], qb1=p2[1], qb2=p2[2];
        float fa[24], fb[24];
        unp24(qa0,qa1,qa2,fa);
        unp24(qb0,qb1,qb2,fb);
        #pragma unroll
        for (int k=0;k<24;k++) acc[k] = fmaf(v1, fa[k], fmaf(v2, fb[k], acc[k]));
    }
    if (e < e1){
        int s1 = col[e];
        float v1 = val[e];
        const uint4* p1 = (const uint4*)(xl + s1*384);
        uint4 qa0=p1[0], qa1=p1[1], qa2=p1[2];
        float fa[24];
        unp24(qa0,qa1,qa2,fa);
        #pragma unroll
        for (int k=0;k<24;k++) acc[k] = fmaf(v1, fa[k], acc[k]);
    }
    if (h == 0){                               // self loop: weight 1/deg_tot
        float v = fast_rcp(deg[n] + 1.0f);
        const uint4* p1 = (const uint4*)(xl + n*384);
        uint4 qa0=p1[0], qa1=p1[1], qa2=p1[2];
        float fa[24];
        unp24(qa0,qa1,qa2,fa);
        #pragma unroll
        for (int k=0;k<24;k++) acc[k] = fmaf(v, fa[k], acc[k]);
    }
    // combine the two edge-halves -> full y in both lanes
    #pragma unroll
    for (int k=0;k<24;k++) acc[k] += __shfl_xor(acc[k], 16, 64);

    // ---- collapsed GRU epilogue: c in [16h, 16h+16) ----
    float pr[12];
    #pragma unroll
    for (int p=0;p<12;p++) pr[p] = wbuf[256+p];        // wave-uniform -> sgpr
    float o[12];
    #pragma unroll
    for (int q=0;q<12;q++) o[q] = 0.f;

    const float4* wp = (const float4*)wbuf;
    int cbase = h*16;
    for (int cc=0; cc<16; ++cc){
        int c = cbase + cc;
        float4 wa = wp[c*2];                           // wz0,wz1,bz,wh0 (scaled)
        float4 wb = wp[c*2+1];                         // wh1,bh,-,-
        float a = 0.f;
        #pragma unroll
        for (int p=0;p<12;p++){
            float y0 = acc[p], y1 = acc[12+p];         // fp = f*12+p
            float zs = fmaf(y1, wa.y, fmaf(y0, wa.x, wa.z));   // log2(e)*zs
            float hs = fmaf(y1, wb.x, fmaf(y0, wa.w, wb.y));   // 2*log2(e)*hs
            zs = fminf(zs, 80.f); hs = fminf(hs, 80.f);
            float ez = fast_exp2(zs);                  // e^zs
            float eh = fast_exp2(hs);                  // e^{2hs}
            float t  = fast_rcp((1.f+ez)*(1.f+eh));
            a = fmaf(pr[p]*(eh-1.f), t, a);            // pr*(1-sig(zs))*tanh(hs)
        }
        a = fmaxf(a, 0.f);                             // relu(H_acc)
        const float4* lw = (const float4*)(wbuf + 288 + c*12);
        float4 w0 = lw[0], w1 = lw[1], w2 = lw[2];
        o[0]=fmaf(a,w0.x,o[0]); o[1]=fmaf(a,w0.y,o[1]); o[2] =fmaf(a,w0.z,o[2]);  o[3] =fmaf(a,w0.w,o[3]);
        o[4]=fmaf(a,w1.x,o[4]); o[5]=fmaf(a,w1.y,o[5]); o[6] =fmaf(a,w1.z,o[6]);  o[7] =fmaf(a,w1.w,o[7]);
        o[8]=fmaf(a,w2.x,o[8]); o[9]=fmaf(a,w2.y,o[9]); o[10]=fmaf(a,w2.z,o[10]); o[11]=fmaf(a,w2.w,o[11]);
    }
    #pragma unroll
    for (int q=0;q<12;q++) o[q] += __shfl_xor(o[q], 16, 64);
    if (h == 0){
        #pragma unroll
        for (int q=0;q<12;q++) o[q] += wbuf[268+q];    // lin_out_b
        float4* op = (float4*)(out + (l*NN + n)*12);   // 48B-aligned
        op[0] = make_float4(o[0],o[1],o[2],o[3]);
        op[1] = make_float4(o[4],o[5],o[6],o[7]);
        op[2] = make_float4(o[8],o[9],o[10],o[11]);
    }
}

extern "C" void kernel_launch(void* const* d_in, const int* in_sizes, int n_in,
                              void* d_out, int out_size, void* d_ws, size_t ws_size,
                              hipStream_t stream) {
    const float* x   = (const float*)d_in[0];      // [B,N,F,P] fp32 (established round 1 vs 2)
    const int*   ei  = (const int*)d_in[1];        // [2,E]
    const float* ew  = (const float*)d_in[2];
    const float* Wz  = (const float*)d_in[3];
    const float* bz  = (const float*)d_in[4];
    const float* LzW = (const float*)d_in[5];
    const float* lzb = (const float*)d_in[6];
    // d_in[7..10]: W_r/b_r/lin_r_W/lin_r_b dead (H0==0)
    const float* Wh  = (const float*)d_in[11];
    const float* bh  = (const float*)d_in[12];
    const float* LhW = (const float*)d_in[13];
    const float* lhb = (const float*)d_in[14];
    const float* att = (const float*)d_in[15];
    const float* LoW = (const float*)d_in[16];
    const float* lob = (const float*)d_in[17];
    float* out = (float*)d_out;

    const int* srcI = ei;
    const int* dstI = ei + EE;

    char* ws = (char*)d_ws;
    size_t off = 0;
    auto alloc = [&](size_t bytes){ void* p = ws + off; off += (bytes + 255)/256*256; return p; };
    int*            degcnt = (int*)alloc(2*NN*4);              // deg (fp32) | cnt (int)
    float*          wbuf   = (float*)alloc(672*4);
    unsigned short* xc     = (unsigned short*)alloc((size_t)XTOT*2);   // 7.68 MB
    int*            rowp   = (int*)alloc((NN+1)*4);
    int*            nxt    = (int*)alloc(NN*4);
    int*            col    = (int*)alloc(EE*4);
    float*          val    = (float*)alloc(EE*4);
    float* deg = (float*)degcnt;
    int*   cnt = degcnt + NN;

    hipMemsetAsync(degcnt, 0, 2*NN*4, stream);
    hipLaunchKernelGGL(k_stage,   dim3(3751), dim3(256),  0, stream,
                       x, ew, dstI, xc, deg, cnt,
                       Wz, bz, LzW, lzb, Wh, bh, LhW, lhb, att, LoW, lob, wbuf);
    hipLaunchKernelGGL(k_scan,    dim3(1),    dim3(1024), 0, stream, cnt, rowp, nxt);
    hipLaunchKernelGGL(k_scatter, dim3(EE/256), dim3(256), 0, stream,
                       srcI, dstI, ew, deg, nxt, col, val);
    hipLaunchKernelGGL(k_fused,   dim3(NN/4), dim3(128),  0, stream,
                       xc, rowp, col, val, deg, wbuf, out);
}